// Round 2
// baseline (1146.281 us; speedup 1.0000x reference)
//
#include <hip/hip_runtime.h>
#include <math.h>

// DCNv2 forward: B=4, Cin=Cout=64, H=W=128, 3x3, stride=1, pad=1, dil=1, groups=dg=1
#define H_    128
#define W_    128
#define HW_   (H_ * W_)
#define CIN_  64
#define COUT_ 64
#define K2_   9
#define P_    64   // output pixels per block (half a row)
#define B_    4

// Pre-transpose weight [Cout][Cin][9] -> wT [9][Cin][Cout] so per-k staging is coalesced.
__global__ __launch_bounds__(256) void wtrans_kernel(const float* __restrict__ w,
                                                     float* __restrict__ wt) {
    int idx = blockIdx.x * 256 + threadIdx.x;
    if (idx >= K2_ * CIN_ * COUT_) return;
    int k   = idx / (CIN_ * COUT_);
    int r   = idx % (CIN_ * COUT_);
    int cin = r >> 6;
    int co  = r & 63;
    wt[idx] = w[co * (CIN_ * K2_) + cin * K2_ + k];
}

__global__ __launch_bounds__(256) void dcn_kernel(
    const float* __restrict__ x,      // [B, Cin, H, W]
    const float* __restrict__ offset, // [B, 18, H, W]  (k*2 = y, k*2+1 = x)
    const float* __restrict__ mask,   // [B, 9, H, W]
    const float* __restrict__ wt,     // [9, Cin, Cout]  (transposed)
    const float* __restrict__ bias,   // [Cout]
    float* __restrict__ out)          // [B, Cout, H, W]
{
    __shared__ float s_samp[CIN_][P_];      // 16 KB
    __shared__ float s_w[CIN_ * COUT_];     // 16 KB

    const int tid  = threadIdx.x;
    const int lane = tid & 63;
    const int wave = tid >> 6;

    // Bijective XCD swizzle: 1024 wgs -> 128 contiguous logical ids per XCD,
    // so each XCD's 4 MB L2 holds ~half of one batch image's x-slab.
    const int bid0 = blockIdx.x;
    const int bidx = (bid0 & 7) * 128 + (bid0 >> 3);

    const int b    = bidx >> 8;
    const int rem  = bidx & 255;
    const int ho   = rem >> 1;
    const int w0   = (rem & 1) * P_;
    const int wo   = w0 + lane;
    const int pix  = ho * W_ + wo;

    const float* xb   = x      + (size_t)b * CIN_ * HW_ + (size_t)(wave * 16) * HW_;
    const float* offb = offset + (size_t)b * 2 * K2_ * HW_ + pix;
    const float* mb   = mask   + (size_t)b * K2_ * HW_ + pix;

    // GEMM register tile: 4 co x 4 px per thread (256 thr = 16 cogroups x 16 pgroups)
    const int pgroup  = tid & 15;
    const int cogroup = tid >> 4;

    float acc[4][4];
#pragma unroll
    for (int i = 0; i < 4; ++i)
#pragma unroll
        for (int j = 0; j < 4; ++j) acc[i][j] = 0.f;

    // pipeline registers
    float  g[16][4];     // pending bilinear gathers for the *next* tap (16 ch x 4 corners)
    float4 wreg[4];      // pending weight k-slice quarter
    float  W00, W01, W10, W11;   // bilinear*mask weights for the pending tap
    float  offyN, offxN, mN;     // offsets/mask for the tap after that

    // issue gathers + weight loads for tap k, using already-loaded offs (oy,ox,mm)
    auto issue = [&](int k, float oy, float ox, float mm) {
        const int ky = k / 3, kx = k % 3;
        const float py = (float)(ho - 1 + ky) + oy;
        const float px = (float)(wo - 1 + kx) + ox;
        const float fy = floorf(py), fx = floorf(px);
        const int   y0 = (int)fy,    x0 = (int)fx;
        const float ly = py - fy,    lx = px - fx;
        const int   y1 = y0 + 1,     x1 = x0 + 1;

        const float vy0 = (y0 >= 0 && y0 < H_) ? 1.f : 0.f;
        const float vy1 = (y1 >= 0 && y1 < H_) ? 1.f : 0.f;
        const float vx0 = (x0 >= 0 && x0 < W_) ? 1.f : 0.f;
        const float vx1 = (x1 >= 0 && x1 < W_) ? 1.f : 0.f;
        const int cy0 = min(max(y0, 0), H_ - 1), cy1 = min(max(y1, 0), H_ - 1);
        const int cx0 = min(max(x0, 0), W_ - 1), cx1 = min(max(x1, 0), W_ - 1);
        const int i00 = cy0 * W_ + cx0, i01 = cy0 * W_ + cx1;
        const int i10 = cy1 * W_ + cx0, i11 = cy1 * W_ + cx1;

        W00 = mm * (1.f - ly) * (1.f - lx) * vy0 * vx0;
        W01 = mm * (1.f - ly) * lx         * vy0 * vx1;
        W10 = mm * ly * (1.f - lx)         * vy1 * vx0;
        W11 = mm * ly * lx                 * vy1 * vx1;

        const float* p = xb;
#pragma unroll
        for (int c = 0; c < 16; ++c) {
            g[c][0] = p[i00];
            g[c][1] = p[i01];
            g[c][2] = p[i10];
            g[c][3] = p[i11];
            p += HW_;
        }
        const float4* src = (const float4*)(wt + (size_t)k * (CIN_ * COUT_));
#pragma unroll
        for (int i = 0; i < 4; ++i) wreg[i] = src[i * 256 + tid];
    };

    // combine pending gathers into LDS (waits on the loads here)
    auto combine_write = [&]() {
#pragma unroll
        for (int c = 0; c < 16; ++c) {
            s_samp[wave * 16 + c][lane] =
                W00 * g[c][0] + W01 * g[c][1] + W10 * g[c][2] + W11 * g[c][3];
        }
        float4* dst = (float4*)s_w;
#pragma unroll
        for (int i = 0; i < 4; ++i) dst[i * 256 + tid] = wreg[i];
    };

    // ---- prologue: tap 0 ----
    {
        const float oy = offb[0];
        const float ox = offb[HW_];
        const float mm = mb[0];
        issue(0, oy, ox, mm);
        // preload offs for tap 1
        offyN = offb[2 * HW_];
        offxN = offb[3 * HW_];
        mN    = mb[HW_];
        combine_write();
    }
    __syncthreads();

#pragma unroll 1
    for (int k = 0; k < K2_; ++k) {
        if (k < K2_ - 1) {
            const float oy = offyN, ox = offxN, mm = mN;
            if (k + 2 < K2_) {   // preload offs for tap k+2 (longest in flight)
                offyN = offb[(2 * (k + 2)) * HW_];
                offxN = offb[(2 * (k + 2) + 1) * HW_];
                mN    = mb[(k + 2) * HW_];
            }
            issue(k + 1, oy, ox, mm);   // gathers fly during the GEMM below
        }

        // ---- rank-64 update from LDS (tap k): acc[co 0..3][px 0..3] ----
#pragma unroll
        for (int cin = 0; cin < CIN_; ++cin) {
            const float4 sv = *(const float4*)&s_samp[cin][pgroup << 2];
            const float4 wv = *(const float4*)&s_w[(cin << 6) + (cogroup << 2)];
            acc[0][0] = fmaf(wv.x, sv.x, acc[0][0]);
            acc[0][1] = fmaf(wv.x, sv.y, acc[0][1]);
            acc[0][2] = fmaf(wv.x, sv.z, acc[0][2]);
            acc[0][3] = fmaf(wv.x, sv.w, acc[0][3]);
            acc[1][0] = fmaf(wv.y, sv.x, acc[1][0]);
            acc[1][1] = fmaf(wv.y, sv.y, acc[1][1]);
            acc[1][2] = fmaf(wv.y, sv.z, acc[1][2]);
            acc[1][3] = fmaf(wv.y, sv.w, acc[1][3]);
            acc[2][0] = fmaf(wv.z, sv.x, acc[2][0]);
            acc[2][1] = fmaf(wv.z, sv.y, acc[2][1]);
            acc[2][2] = fmaf(wv.z, sv.z, acc[2][2]);
            acc[2][3] = fmaf(wv.z, sv.w, acc[2][3]);
            acc[3][0] = fmaf(wv.w, sv.x, acc[3][0]);
            acc[3][1] = fmaf(wv.w, sv.y, acc[3][1]);
            acc[3][2] = fmaf(wv.w, sv.z, acc[3][2]);
            acc[3][3] = fmaf(wv.w, sv.w, acc[3][3]);
        }

        if (k < K2_ - 1) {
            __syncthreads();     // everyone done reading tap k
            combine_write();     // waits on pending gathers (long done), overwrites LDS
            __syncthreads();     // tap k+1 visible
        }
    }

    // ---- epilogue: add bias, coalesced float4 stores ----
#pragma unroll
    for (int i = 0; i < 4; ++i) {
        const int co = cogroup * 4 + i;
        const float bv = bias[co];
        float4 o;
        o.x = acc[i][0] + bv;
        o.y = acc[i][1] + bv;
        o.z = acc[i][2] + bv;
        o.w = acc[i][3] + bv;
        *(float4*)&out[((size_t)(b * COUT_ + co)) * HW_ + ho * W_ + w0 + (pgroup << 2)] = o;
    }
}

extern "C" void kernel_launch(void* const* d_in, const int* in_sizes, int n_in,
                              void* d_out, int out_size, void* d_ws, size_t ws_size,
                              hipStream_t stream) {
    const float* x      = (const float*)d_in[0];
    const float* offset = (const float*)d_in[1];
    const float* mask   = (const float*)d_in[2];
    const float* weight = (const float*)d_in[3];
    const float* bias   = (const float*)d_in[4];
    float* out = (float*)d_out;
    float* wt  = (float*)d_ws;  // 9*64*64*4 = 147456 bytes

    wtrans_kernel<<<(K2_ * CIN_ * COUT_ + 255) / 256, 256, 0, stream>>>(weight, wt);
    dcn_kernel<<<B_ * H_ * (W_ / P_), 256, 0, stream>>>(x, offset, mask, wt, bias, out);
}

// Round 3
// 139.499 us; speedup vs baseline: 8.2171x; 8.2171x over previous
//
#include <hip/hip_runtime.h>
#include <math.h>

// DCNv2 forward: B=4, Cin=Cout=64, H=W=128, 3x3, stride=1, pad=1, dil=1, groups=dg=1
#define H_    128
#define W_    128
#define HW_   (H_ * W_)
#define CIN_  64
#define COUT_ 64
#define K2_   9
#define P_    32   // output pixels per block (quarter row) -> 2048 blocks for TLP
#define B_    4

// Pre-transpose weight [Cout][Cin][9] -> wT [9][Cin][Cout] so per-k staging is coalesced.
__global__ __launch_bounds__(256) void wtrans_kernel(const float* __restrict__ w,
                                                     float* __restrict__ wt) {
    int idx = blockIdx.x * 256 + threadIdx.x;
    if (idx >= K2_ * CIN_ * COUT_) return;
    int k   = idx / (CIN_ * COUT_);
    int r   = idx % (CIN_ * COUT_);
    int cin = r >> 6;
    int co  = r & 63;
    wt[idx] = w[co * (CIN_ * K2_) + cin * K2_ + k];
}

__global__ __launch_bounds__(256, 5) void dcn_kernel(
    const float* __restrict__ x,      // [B, Cin, H, W]
    const float* __restrict__ offset, // [B, 18, H, W]
    const float* __restrict__ mask,   // [B, 9, H, W]
    const float* __restrict__ wt,     // [9, Cin, Cout]
    const float* __restrict__ bias,   // [Cout]
    float* __restrict__ out)          // [B, Cout, H, W]
{
    __shared__ float s_samp[CIN_][P_];   // 8 KB
    __shared__ float s_w[CIN_ * COUT_];  // 16 KB

    const int tid = threadIdx.x;

    // sampling mapping: 32 px x 8 channel-chunks (8 ch each)
    const int spx   = tid & 31;
    const int chunk = tid >> 5;

    // GEMM mapping: 8 px-groups (4 px) x 32 co-groups (2 co)
    const int pg = tid & 7;
    const int cg = tid >> 3;

    // Bijective XCD swizzle: 2048 wgs -> 256 contiguous logical ids per XCD
    // (one XCD = one batch's 64-row slab; x working set ~2 MB < 4 MB L2)
    const int bid0 = blockIdx.x;
    const int bidx = (bid0 & 7) * 256 + (bid0 >> 3);

    const int b   = bidx >> 9;
    const int rem = bidx & 511;
    const int ho  = rem >> 2;
    const int w0  = (rem & 3) * P_;
    const int wos = w0 + spx;
    const int pix = ho * W_ + wos;

    const float* xb   = x + (size_t)b * CIN_ * HW_ + (size_t)(chunk * 8) * HW_;
    const float* offb = offset + (size_t)b * (2 * K2_) * HW_ + pix;
    const float* mb   = mask   + (size_t)b * K2_ * HW_ + pix;

    float acc[2][4];
#pragma unroll
    for (int i = 0; i < 2; ++i)
#pragma unroll
        for (int j = 0; j < 4; ++j) acc[i][j] = 0.f;

    // offsets for current tap (prefetched one tap ahead)
    float oy = offb[0];
    float ox = offb[HW_];
    float mm = mb[0];

#pragma unroll 1
    for (int k = 0; k < K2_; ++k) {
        const int ky = k / 3, kx = k % 3;
        const float py  = (float)(ho - 1 + ky) + oy;
        const float pxf = (float)(wos - 1 + kx) + ox;
        const float fy = floorf(py), fx = floorf(pxf);
        const int   y0 = (int)fy,    x0 = (int)fx;
        const float ly = py - fy,    lx = pxf - fx;

        // row weights with validity folded
        const float A0 = (y0 >= 0 && y0 < H_)         ? (1.f - ly) : 0.f;
        const float A1 = (y0 + 1 >= 0 && y0 + 1 < H_) ? ly         : 0.f;
        // column weights (mask + validity folded), mapped onto the float2 pair
        const float vx0 = (x0 >= 0 && x0 < W_)         ? 1.f : 0.f;
        const float vx1 = (x0 + 1 >= 0 && x0 + 1 < W_) ? 1.f : 0.f;
        const float cl = mm * (1.f - lx) * vx0;
        const float cr = mm * lx * vx1;
        const int cy0 = min(max(y0, 0), H_ - 1);
        const int cy1 = min(max(y0 + 1, 0), H_ - 1);
        const int cxb = min(max(x0, 0), W_ - 2);       // float2 covers cols cxb, cxb+1
        const float wxx = (x0 >= W_ - 1) ? 0.f : ((x0 < 0) ? cr : cl);
        const float wxy = (x0 >= W_ - 1) ? cl  : ((x0 < 0) ? 0.f : cr);

        __syncthreads();   // prior GEMM finished reading s_samp / s_w

        // ---- gather (paired-column float2) + combine into LDS ----
        {
            const float* p0 = xb + cy0 * W_ + cxb;
            const float* p1 = xb + cy1 * W_ + cxb;
#pragma unroll
            for (int c = 0; c < 8; ++c) {
                const float2 r0 = *(const float2*)p0;
                const float2 r1 = *(const float2*)p1;
                const float v0 = fmaf(wxx, r0.x, wxy * r0.y);
                const float v1 = fmaf(wxx, r1.x, wxy * r1.y);
                s_samp[chunk * 8 + c][spx] = fmaf(A0, v0, A1 * v1);
                p0 += HW_; p1 += HW_;
            }
        }
        // ---- stage weight k-slice [cin][co] ----
        {
            const float4* src = (const float4*)(wt + (size_t)k * (CIN_ * COUT_));
            float4*       dst = (float4*)s_w;
#pragma unroll
            for (int i = 0; i < 4; ++i)
                dst[i * 256 + tid] = src[i * 256 + tid];
        }
        // prefetch next tap's offsets (latency hidden under GEMM)
        if (k + 1 < K2_) {
            oy = offb[(2 * (k + 1)) * HW_];
            ox = offb[(2 * (k + 1) + 1) * HW_];
            mm = mb[(k + 1) * HW_];
        }

        __syncthreads();

        // ---- rank-64 update: acc[co 0..1][px 0..3] ----
#pragma unroll
        for (int cin = 0; cin < CIN_; ++cin) {
            const float4 sv = *(const float4*)&s_samp[cin][pg << 2];
            const float2 wv = *(const float2*)&s_w[(cin << 6) + (cg << 1)];
            acc[0][0] = fmaf(wv.x, sv.x, acc[0][0]);
            acc[0][1] = fmaf(wv.x, sv.y, acc[0][1]);
            acc[0][2] = fmaf(wv.x, sv.z, acc[0][2]);
            acc[0][3] = fmaf(wv.x, sv.w, acc[0][3]);
            acc[1][0] = fmaf(wv.y, sv.x, acc[1][0]);
            acc[1][1] = fmaf(wv.y, sv.y, acc[1][1]);
            acc[1][2] = fmaf(wv.y, sv.z, acc[1][2]);
            acc[1][3] = fmaf(wv.y, sv.w, acc[1][3]);
        }
    }

    // ---- epilogue ----
#pragma unroll
    for (int i = 0; i < 2; ++i) {
        const int co = (cg << 1) + i;
        const float bv = bias[co];
        float4 o;
        o.x = acc[i][0] + bv;
        o.y = acc[i][1] + bv;
        o.z = acc[i][2] + bv;
        o.w = acc[i][3] + bv;
        *(float4*)&out[((size_t)(b * COUT_ + co)) * HW_ + ho * W_ + w0 + (pg << 2)] = o;
    }
}

extern "C" void kernel_launch(void* const* d_in, const int* in_sizes, int n_in,
                              void* d_out, int out_size, void* d_ws, size_t ws_size,
                              hipStream_t stream) {
    const float* x      = (const float*)d_in[0];
    const float* offset = (const float*)d_in[1];
    const float* mask   = (const float*)d_in[2];
    const float* weight = (const float*)d_in[3];
    const float* bias   = (const float*)d_in[4];
    float* out = (float*)d_out;
    float* wt  = (float*)d_ws;  // 9*64*64*4 = 147456 bytes

    wtrans_kernel<<<(K2_ * CIN_ * COUT_ + 255) / 256, 256, 0, stream>>>(weight, wt);
    dcn_kernel<<<B_ * H_ * (W_ / P_), 256, 0, stream>>>(x, offset, mask, wt, bias, out);
}

// Round 4
// 118.589 us; speedup vs baseline: 9.6660x; 1.1763x over previous
//
#include <hip/hip_runtime.h>
#include <math.h>

// DCNv2 forward: B=4, Cin=Cout=64, H=W=128, 3x3, stride=1, pad=1, dil=1, groups=dg=1
#define H_    128
#define W_    128
#define HW_   (H_ * W_)
#define CIN_  64
#define COUT_ 64
#define K2_   9
#define B_    4

typedef __bf16 bf16x8 __attribute__((ext_vector_type(8)));
typedef float  f32x4  __attribute__((ext_vector_type(4)));

// weight [Cout][Cin][3][3] (fp32) -> wt [9][Cout][Cin] (bf16)
__global__ __launch_bounds__(256) void wtrans_kernel(const float* __restrict__ w,
                                                     __bf16* __restrict__ wt) {
    int idx = blockIdx.x * 256 + threadIdx.x;
    if (idx >= K2_ * COUT_ * CIN_) return;
    int k   = idx / (COUT_ * CIN_);
    int r   = idx % (COUT_ * CIN_);
    int co  = r >> 6;
    int cin = r & 63;
    wt[idx] = (__bf16)w[co * (CIN_ * K2_) + cin * K2_ + k];
}

// Zero-LDS, zero-barrier fused DCNv2:
//  - each wave owns 16 output pixels x all 64 Cout
//  - sampled values are produced directly in MFMA B-fragment layout
//    (lane = px + 16*kblock, holding 8 consecutive cin)
//  - A-fragments (weights) read 16B-contiguous from bf16 wt[9][co][cin]
__global__ __launch_bounds__(256, 4) void dcn_kernel(
    const float* __restrict__ x,      // [B, Cin, H, W]
    const float* __restrict__ offset, // [B, 18, H, W]
    const float* __restrict__ mask,   // [B, 9, H, W]
    const __bf16* __restrict__ wt,    // [9, Cout, Cin] bf16
    const float* __restrict__ bias,   // [Cout]
    float* __restrict__ out)          // [B, Cout, H, W]
{
    const int tid  = threadIdx.x;
    const int wave = tid >> 6;
    const int lane = tid & 63;
    const int n16  = lane & 15;   // pixel within the wave's 16-px tile (B/D col)
    const int kb   = lane >> 4;   // k-block 0..3 (cin block for B, row block for D)

    // Bijective XCD swizzle: 1024 wgs -> 128 contiguous logical ids per XCD
    const int bid0 = blockIdx.x;
    const int bidx = (bid0 & 7) * 128 + (bid0 >> 3);

    const int b   = bidx >> 8;
    const int rem = bidx & 255;
    const int ho  = rem >> 1;
    const int w0  = (rem & 1) * 64 + wave * 16;  // this wave's 16-px tile base
    const int wos = w0 + n16;
    const int pix = ho * W_ + wos;

    const float* xb   = x + (size_t)b * CIN_ * HW_;
    const float* offb = offset + (size_t)b * (2 * K2_) * HW_ + pix;
    const float* mb   = mask   + (size_t)b * K2_ * HW_ + pix;

    const int cin0 = kb * 8;        // B-frag cin block for K-step 0
    const int cin1 = kb * 8 + 32;   // ... for K-step 1

    f32x4 acc[4];
#pragma unroll
    for (int t = 0; t < 4; ++t) acc[t] = (f32x4){0.f, 0.f, 0.f, 0.f};

    // prefetch tap 0 offsets
    float oy = offb[0];
    float ox = offb[HW_];
    float mm = mb[0];

#pragma unroll 1
    for (int k = 0; k < K2_; ++k) {
        const int ky = k / 3, kx = k % 3;
        const float py  = (float)(ho - 1 + ky) + oy;
        const float pxf = (float)(wos - 1 + kx) + ox;
        const float fy = floorf(py), fx = floorf(pxf);
        const int   y0 = (int)fy,    x0 = (int)fx;
        const float ly = py - fy,    lx = pxf - fx;

        // row weights with validity folded
        const float A0 = (y0 >= 0 && y0 < H_)         ? (1.f - ly) : 0.f;
        const float A1 = (y0 + 1 >= 0 && y0 + 1 < H_) ? ly         : 0.f;
        // column weights (mask + validity folded), on the clamped float2 pair
        const float vx0 = (x0 >= 0 && x0 < W_)         ? 1.f : 0.f;
        const float vx1 = (x0 + 1 >= 0 && x0 + 1 < W_) ? 1.f : 0.f;
        const float cl = mm * (1.f - lx) * vx0;
        const float cr = mm * lx * vx1;
        const int cy0 = min(max(y0, 0), H_ - 1);
        const int cy1 = min(max(y0 + 1, 0), H_ - 1);
        const int cxb = min(max(x0, 0), W_ - 2);
        const float wxx = (x0 >= W_ - 1) ? 0.f : ((x0 < 0) ? cr : cl);
        const float wxy = (x0 >= W_ - 1) ? cl  : ((x0 < 0) ? 0.f : cr);

        // prefetch next tap's offsets (hidden under gathers + MFMA)
        if (k + 1 < K2_) {
            oy = offb[(2 * (k + 1)) * HW_];
            ox = offb[(2 * (k + 1) + 1) * HW_];
            mm = mb[(k + 1) * HW_];
        }

        // ---- sample 16 channels (2 cin blocks of 8) for this lane's pixel ----
        const float* q0 = xb + (size_t)cin0 * HW_ + cy0 * W_ + cxb;
        const float* q1 = xb + (size_t)cin0 * HW_ + cy1 * W_ + cxb;

        bf16x8 bf0, bf1;
#pragma unroll
        for (int c = 0; c < 8; ++c) {
            const float2 r0 = *(const float2*)(q0 + (size_t)c * HW_);
            const float2 r1 = *(const float2*)(q1 + (size_t)c * HW_);
            const float v = fmaf(A0, fmaf(wxx, r0.x, wxy * r0.y),
                                 A1 * fmaf(wxx, r1.x, wxy * r1.y));
            bf0[c] = (__bf16)v;
        }
        const float* q2 = q0 + (size_t)32 * HW_;
        const float* q3 = q1 + (size_t)32 * HW_;
#pragma unroll
        for (int c = 0; c < 8; ++c) {
            const float2 r0 = *(const float2*)(q2 + (size_t)c * HW_);
            const float2 r1 = *(const float2*)(q3 + (size_t)c * HW_);
            const float v = fmaf(A0, fmaf(wxx, r0.x, wxy * r0.y),
                                 A1 * fmaf(wxx, r1.x, wxy * r1.y));
            bf1[c] = (__bf16)v;
        }

        // ---- 8 MFMAs: 4 co-tiles x 2 K-steps ----
        const __bf16* wk = wt + (size_t)k * (COUT_ * CIN_) + (size_t)n16 * CIN_;
#pragma unroll
        for (int ct = 0; ct < 4; ++ct) {
            const __bf16* wrow = wk + (size_t)(ct * 16) * CIN_;
            const bf16x8 a0 = *(const bf16x8*)(wrow + cin0);
            const bf16x8 a1 = *(const bf16x8*)(wrow + cin1);
            acc[ct] = __builtin_amdgcn_mfma_f32_16x16x32_bf16(a0, bf0, acc[ct], 0, 0, 0);
            acc[ct] = __builtin_amdgcn_mfma_f32_16x16x32_bf16(a1, bf1, acc[ct], 0, 0, 0);
        }
    }

    // ---- epilogue: D col = lane&15 (px), row = kb*4 + r (+ ct*16) ----
#pragma unroll
    for (int ct = 0; ct < 4; ++ct) {
#pragma unroll
        for (int r = 0; r < 4; ++r) {
            const int co = ct * 16 + kb * 4 + r;
            out[((size_t)(b * COUT_ + co)) * HW_ + pix] = acc[ct][r] + bias[co];
        }
    }
}

extern "C" void kernel_launch(void* const* d_in, const int* in_sizes, int n_in,
                              void* d_out, int out_size, void* d_ws, size_t ws_size,
                              hipStream_t stream) {
    const float* x      = (const float*)d_in[0];
    const float* offset = (const float*)d_in[1];
    const float* mask   = (const float*)d_in[2];
    const float* weight = (const float*)d_in[3];
    const float* bias   = (const float*)d_in[4];
    float*  out = (float*)d_out;
    __bf16* wtb = (__bf16*)d_ws;  // 9*64*64*2 = 73728 bytes

    wtrans_kernel<<<(K2_ * COUT_ * CIN_ + 255) / 256, 256, 0, stream>>>(weight, wtb);
    // 1024 blocks x 256 threads; each block = 4 waves x (16 px x 64 co)
    dcn_kernel<<<B_ * H_ * 2, 256, 0, stream>>>(x, offset, mask, wtb, bias, out);
}

// Round 5
// 63.235 us; speedup vs baseline: 18.1274x; 1.8754x over previous
//
#include <hip/hip_runtime.h>
#include <math.h>

// DCNv2 forward: B=4, Cin=Cout=64, H=W=128, 3x3, stride=1, pad=1, dil=1, groups=dg=1
#define H_    128
#define W_    128
#define HW_   (H_ * W_)
#define CIN_  64
#define COUT_ 64
#define K2_   9
#define B_    4

typedef __bf16 bf16x8 __attribute__((ext_vector_type(8)));
typedef float  f32x4  __attribute__((ext_vector_type(4)));

// ---------------------------------------------------------------------------
// NHWC path kernels
// ---------------------------------------------------------------------------

// weight [Cout][Cin][3][3] -> lane-linear MFMA A-frag layout:
// wt3[k][s][ct][lane][e] = weight[ct*16+(lane&15)][s*32+(lane>>4)*8+e][k]
__global__ __launch_bounds__(256) void wtrans3_kernel(const float* __restrict__ w,
                                                      __bf16* __restrict__ wt3) {
    int idx = blockIdx.x * 256 + threadIdx.x;     // 9*2*4*64*8 = 36864
    if (idx >= K2_ * 2 * 4 * 64 * 8) return;
    int e    = idx & 7;
    int lane = (idx >> 3) & 63;
    int ct   = (idx >> 9) & 3;
    int s    = (idx >> 11) & 1;
    int k    = idx >> 12;
    int co   = ct * 16 + (lane & 15);
    int cin  = s * 32 + (lane >> 4) * 8 + e;
    wt3[idx] = (__bf16)w[(co * CIN_ + cin) * K2_ + k];
}

// x [B][C][H][W] fp32 -> xn [B][H][W][C] bf16 (LDS tile transpose per (b,h) row)
__global__ __launch_bounds__(256) void repack_kernel(const float* __restrict__ x,
                                                     __bf16* __restrict__ xn) {
    __shared__ float tile[CIN_][W_ + 1];   // 33 KB
    const int bh = blockIdx.x;             // 512 blocks
    const int b  = bh >> 7, h = bh & 127;
    const int tid = threadIdx.x;

    const float* src = x + (size_t)b * CIN_ * HW_ + h * W_;
#pragma unroll
    for (int i = 0; i < 8; ++i) {
        int idx = i * 256 + tid;           // float4 index 0..2047
        int c = idx >> 5;                  // 32 float4 per channel row
        int f = idx & 31;
        float4 v = *(const float4*)(src + (size_t)c * HW_ + f * 4);
        tile[c][f * 4 + 0] = v.x;
        tile[c][f * 4 + 1] = v.y;
        tile[c][f * 4 + 2] = v.z;
        tile[c][f * 4 + 3] = v.w;
    }
    __syncthreads();

    const int w  = tid >> 1;
    const int c0 = (tid & 1) * 32;
    __bf16* dst = xn + (((size_t)(b * H_ + h)) * W_ + w) * CIN_ + c0;
#pragma unroll
    for (int j = 0; j < 4; ++j) {
        bf16x8 o;
#pragma unroll
        for (int e = 0; e < 8; ++e) o[e] = (__bf16)tile[c0 + j * 8 + e][w];
        *(bf16x8*)(dst + j * 8) = o;
    }
}

// Zero-LDS, zero-barrier fused DCNv2 with NHWC bf16 gathers.
__global__ __launch_bounds__(256, 4) void dcn_nhwc_kernel(
    const __bf16* __restrict__ xn,     // [B, H, W, Cin] bf16
    const float* __restrict__ offset,  // [B, 18, H, W]
    const float* __restrict__ mask,    // [B, 9, H, W]
    const __bf16* __restrict__ wt3,    // lane-linear A-frags
    const float* __restrict__ bias,
    float* __restrict__ out)           // [B, Cout, H, W]
{
    const int tid  = threadIdx.x;
    const int wave = tid >> 6;
    const int lane = tid & 63;
    const int n16  = lane & 15;
    const int kb   = lane >> 4;

    const int bid0 = blockIdx.x;
    const int bidx = (bid0 & 7) * 128 + (bid0 >> 3);   // bijective XCD swizzle

    const int b   = bidx >> 8;
    const int rem = bidx & 255;
    const int ho  = rem >> 1;
    const int w0  = (rem & 1) * 64 + wave * 16;
    const int wos = w0 + n16;
    const int pix = ho * W_ + wos;

    const __bf16* xnb = xn + (size_t)b * HW_ * CIN_;
    const float* offb = offset + (size_t)b * (2 * K2_) * HW_ + pix;
    const float* mb   = mask   + (size_t)b * K2_ * HW_ + pix;

    const int cin0 = kb * 8;
    const int cin1 = 32 + kb * 8;

    f32x4 acc[4];
#pragma unroll
    for (int t = 0; t < 4; ++t) acc[t] = (f32x4){0.f, 0.f, 0.f, 0.f};

    float oy = offb[0];
    float ox = offb[HW_];
    float mm = mb[0];

#pragma unroll 1
    for (int k = 0; k < K2_; ++k) {
        const int ky = k / 3, kx = k % 3;
        const float py  = (float)(ho - 1 + ky) + oy;
        const float pxf = (float)(wos - 1 + kx) + ox;
        const float fy = floorf(py), fx = floorf(pxf);
        const int   y0 = (int)fy,    x0 = (int)fx;
        const float ly = py - fy,    lx = pxf - fx;

        const float vy0 = (y0 >= 0 && y0 < H_)         ? 1.f : 0.f;
        const float vy1 = (y0 + 1 >= 0 && y0 + 1 < H_) ? 1.f : 0.f;
        const float vx0 = (x0 >= 0 && x0 < W_)         ? 1.f : 0.f;
        const float vx1 = (x0 + 1 >= 0 && x0 + 1 < W_) ? 1.f : 0.f;
        const float W00 = mm * (1.f - ly) * (1.f - lx) * vy0 * vx0;
        const float W01 = mm * (1.f - ly) * lx         * vy0 * vx1;
        const float W10 = mm * ly * (1.f - lx)         * vy1 * vx0;
        const float W11 = mm * ly * lx                 * vy1 * vx1;
        const int cy0 = min(max(y0, 0), H_ - 1);
        const int cy1 = min(max(y0 + 1, 0), H_ - 1);
        const int cx0 = min(max(x0, 0), W_ - 1);
        const int cx1 = min(max(x0 + 1, 0), W_ - 1);

        const __bf16* p00 = xnb + (size_t)(cy0 * W_ + cx0) * CIN_;
        const __bf16* p01 = xnb + (size_t)(cy0 * W_ + cx1) * CIN_;
        const __bf16* p10 = xnb + (size_t)(cy1 * W_ + cx0) * CIN_;
        const __bf16* p11 = xnb + (size_t)(cy1 * W_ + cx1) * CIN_;

        const bf16x8 a00 = *(const bf16x8*)(p00 + cin0), b00 = *(const bf16x8*)(p00 + cin1);
        const bf16x8 a01 = *(const bf16x8*)(p01 + cin0), b01 = *(const bf16x8*)(p01 + cin1);
        const bf16x8 a10 = *(const bf16x8*)(p10 + cin0), b10 = *(const bf16x8*)(p10 + cin1);
        const bf16x8 a11 = *(const bf16x8*)(p11 + cin0), b11 = *(const bf16x8*)(p11 + cin1);

        if (k + 1 < K2_) {   // prefetch next tap's offsets under blend+MFMA
            oy = offb[(2 * (k + 1)) * HW_];
            ox = offb[(2 * (k + 1) + 1) * HW_];
            mm = mb[(k + 1) * HW_];
        }

        bf16x8 bf0, bf1;
#pragma unroll
        for (int e = 0; e < 8; ++e) {
            const float v0 = W00 * (float)a00[e] + W01 * (float)a01[e]
                           + W10 * (float)a10[e] + W11 * (float)a11[e];
            const float v1 = W00 * (float)b00[e] + W01 * (float)b01[e]
                           + W10 * (float)b10[e] + W11 * (float)b11[e];
            bf0[e] = (__bf16)v0;
            bf1[e] = (__bf16)v1;
        }

        const __bf16* wk = wt3 + (size_t)k * (2 * 4 * 64 * 8);
#pragma unroll
        for (int ct = 0; ct < 4; ++ct) {
            const bf16x8 A0 = *(const bf16x8*)(wk + (0 * 4 + ct) * 512 + lane * 8);
            const bf16x8 A1 = *(const bf16x8*)(wk + (1 * 4 + ct) * 512 + lane * 8);
            acc[ct] = __builtin_amdgcn_mfma_f32_16x16x32_bf16(A0, bf0, acc[ct], 0, 0, 0);
            acc[ct] = __builtin_amdgcn_mfma_f32_16x16x32_bf16(A1, bf1, acc[ct], 0, 0, 0);
        }
    }

#pragma unroll
    for (int ct = 0; ct < 4; ++ct) {
#pragma unroll
        for (int r = 0; r < 4; ++r) {
            const int co = ct * 16 + kb * 4 + r;
            out[((size_t)(b * COUT_ + co)) * HW_ + pix] = acc[ct][r] + bias[co];
        }
    }
}

// ---------------------------------------------------------------------------
// Fallback path (round-4 kernel, NCHW gathers) — used only if ws too small
// ---------------------------------------------------------------------------

__global__ __launch_bounds__(256) void wtrans_kernel(const float* __restrict__ w,
                                                     __bf16* __restrict__ wt) {
    int idx = blockIdx.x * 256 + threadIdx.x;
    if (idx >= K2_ * COUT_ * CIN_) return;
    int k   = idx / (COUT_ * CIN_);
    int r   = idx % (COUT_ * CIN_);
    int co  = r >> 6;
    int cin = r & 63;
    wt[idx] = (__bf16)w[co * (CIN_ * K2_) + cin * K2_ + k];
}

__global__ __launch_bounds__(256, 4) void dcn_kernel(
    const float* __restrict__ x, const float* __restrict__ offset,
    const float* __restrict__ mask, const __bf16* __restrict__ wt,
    const float* __restrict__ bias, float* __restrict__ out)
{
    const int tid  = threadIdx.x;
    const int wave = tid >> 6;
    const int lane = tid & 63;
    const int n16  = lane & 15;
    const int kb   = lane >> 4;
    const int bid0 = blockIdx.x;
    const int bidx = (bid0 & 7) * 128 + (bid0 >> 3);
    const int b   = bidx >> 8;
    const int rem = bidx & 255;
    const int ho  = rem >> 1;
    const int w0  = (rem & 1) * 64 + wave * 16;
    const int wos = w0 + n16;
    const int pix = ho * W_ + wos;
    const float* xb   = x + (size_t)b * CIN_ * HW_;
    const float* offb = offset + (size_t)b * (2 * K2_) * HW_ + pix;
    const float* mb   = mask   + (size_t)b * K2_ * HW_ + pix;
    const int cin0 = kb * 8;
    f32x4 acc[4];
#pragma unroll
    for (int t = 0; t < 4; ++t) acc[t] = (f32x4){0.f, 0.f, 0.f, 0.f};
    float oy = offb[0], ox = offb[HW_], mm = mb[0];
#pragma unroll 1
    for (int k = 0; k < K2_; ++k) {
        const int ky = k / 3, kx = k % 3;
        const float py  = (float)(ho - 1 + ky) + oy;
        const float pxf = (float)(wos - 1 + kx) + ox;
        const float fy = floorf(py), fx = floorf(pxf);
        const int   y0 = (int)fy,    x0 = (int)fx;
        const float ly = py - fy,    lx = pxf - fx;
        const float A0 = (y0 >= 0 && y0 < H_)         ? (1.f - ly) : 0.f;
        const float A1 = (y0 + 1 >= 0 && y0 + 1 < H_) ? ly         : 0.f;
        const float vx0 = (x0 >= 0 && x0 < W_)         ? 1.f : 0.f;
        const float vx1 = (x0 + 1 >= 0 && x0 + 1 < W_) ? 1.f : 0.f;
        const float cl = mm * (1.f - lx) * vx0;
        const float cr = mm * lx * vx1;
        const int cy0 = min(max(y0, 0), H_ - 1);
        const int cy1 = min(max(y0 + 1, 0), H_ - 1);
        const int cxb = min(max(x0, 0), W_ - 2);
        const float wxx = (x0 >= W_ - 1) ? 0.f : ((x0 < 0) ? cr : cl);
        const float wxy = (x0 >= W_ - 1) ? cl  : ((x0 < 0) ? 0.f : cr);
        if (k + 1 < K2_) {
            oy = offb[(2 * (k + 1)) * HW_];
            ox = offb[(2 * (k + 1) + 1) * HW_];
            mm = mb[(k + 1) * HW_];
        }
        const float* q0 = xb + (size_t)cin0 * HW_ + cy0 * W_ + cxb;
        const float* q1 = xb + (size_t)cin0 * HW_ + cy1 * W_ + cxb;
        bf16x8 bf0, bf1;
#pragma unroll
        for (int c = 0; c < 8; ++c) {
            const float2 r0 = *(const float2*)(q0 + (size_t)c * HW_);
            const float2 r1 = *(const float2*)(q1 + (size_t)c * HW_);
            bf0[c] = (__bf16)fmaf(A0, fmaf(wxx, r0.x, wxy * r0.y),
                                  A1 * fmaf(wxx, r1.x, wxy * r1.y));
        }
        const float* q2 = q0 + (size_t)32 * HW_;
        const float* q3 = q1 + (size_t)32 * HW_;
#pragma unroll
        for (int c = 0; c < 8; ++c) {
            const float2 r0 = *(const float2*)(q2 + (size_t)c * HW_);
            const float2 r1 = *(const float2*)(q3 + (size_t)c * HW_);
            bf1[c] = (__bf16)fmaf(A0, fmaf(wxx, r0.x, wxy * r0.y),
                                  A1 * fmaf(wxx, r1.x, wxy * r1.y));
        }
        const __bf16* wk = wt + (size_t)k * (COUT_ * CIN_) + (size_t)n16 * CIN_;
#pragma unroll
        for (int ct = 0; ct < 4; ++ct) {
            const __bf16* wrow = wk + (size_t)(ct * 16) * CIN_;
            const bf16x8 a0 = *(const bf16x8*)(wrow + cin0);
            const bf16x8 a1 = *(const bf16x8*)(wrow + cin0 + 32);
            acc[ct] = __builtin_amdgcn_mfma_f32_16x16x32_bf16(a0, bf0, acc[ct], 0, 0, 0);
            acc[ct] = __builtin_amdgcn_mfma_f32_16x16x32_bf16(a1, bf1, acc[ct], 0, 0, 0);
        }
    }
#pragma unroll
    for (int ct = 0; ct < 4; ++ct)
#pragma unroll
        for (int r = 0; r < 4; ++r) {
            const int co = ct * 16 + kb * 4 + r;
            out[((size_t)(b * COUT_ + co)) * HW_ + pix] = acc[ct][r] + bias[co];
        }
}

// ---------------------------------------------------------------------------

extern "C" void kernel_launch(void* const* d_in, const int* in_sizes, int n_in,
                              void* d_out, int out_size, void* d_ws, size_t ws_size,
                              hipStream_t stream) {
    const float* x      = (const float*)d_in[0];
    const float* offset = (const float*)d_in[1];
    const float* mask   = (const float*)d_in[2];
    const float* weight = (const float*)d_in[3];
    const float* bias   = (const float*)d_in[4];
    float* out = (float*)d_out;

    const size_t wt_bytes = (size_t)K2_ * COUT_ * CIN_ * 2;        // 73728
    const size_t xn_bytes = (size_t)B_ * HW_ * CIN_ * 2;           // 8388608

    if (ws_size >= wt_bytes + xn_bytes) {
        __bf16* wt3 = (__bf16*)d_ws;
        __bf16* xn  = (__bf16*)((char*)d_ws + wt_bytes);
        wtrans3_kernel<<<(K2_ * 2 * 4 * 64 * 8 + 255) / 256, 256, 0, stream>>>(weight, wt3);
        repack_kernel<<<B_ * H_, 256, 0, stream>>>(x, xn);
        dcn_nhwc_kernel<<<B_ * H_ * 2, 256, 0, stream>>>(xn, offset, mask, wt3, bias, out);
    } else {
        __bf16* wtb = (__bf16*)d_ws;
        wtrans_kernel<<<(K2_ * COUT_ * CIN_ + 255) / 256, 256, 0, stream>>>(weight, wtb);
        dcn_kernel<<<B_ * H_ * 2, 256, 0, stream>>>(x, offset, mask, wtb, bias, out);
    }
}

// Round 6
// 59.846 us; speedup vs baseline: 19.1538x; 1.0566x over previous
//
#include <hip/hip_runtime.h>
#include <math.h>

// DCNv2 forward: B=4, Cin=Cout=64, H=W=128, 3x3, stride=1, pad=1, dil=1, groups=dg=1
#define H_    128
#define W_    128
#define HW_   (H_ * W_)
#define CIN_  64
#define COUT_ 64
#define K2_   9
#define B_    4

typedef __bf16 bf16x8 __attribute__((ext_vector_type(8)));
typedef float  f32x4  __attribute__((ext_vector_type(4)));

// Merged prep: blocks 0..511 repack x [B][C][H][W] fp32 -> xn [B][H][W][C] bf16;
// blocks 512..655 transform weight -> lane-linear MFMA A-frag layout
// wt3[k][s][ct][lane][e] = weight[ct*16+(lane&15)][s*32+(lane>>4)*8+e][k]
__global__ __launch_bounds__(256) void prep_kernel(const float* __restrict__ x,
                                                   const float* __restrict__ w,
                                                   __bf16* __restrict__ xn,
                                                   __bf16* __restrict__ wt3) {
    const int tid = threadIdx.x;
    if (blockIdx.x < 512) {
        __shared__ float tile[CIN_][W_ + 1];   // 33 KB
        const int bh = blockIdx.x;
        const int b  = bh >> 7, h = bh & 127;
        const float* src = x + (size_t)b * CIN_ * HW_ + h * W_;
#pragma unroll
        for (int i = 0; i < 8; ++i) {
            int idx = i * 256 + tid;
            int c = idx >> 5;
            int f = idx & 31;
            float4 v = *(const float4*)(src + (size_t)c * HW_ + f * 4);
            tile[c][f * 4 + 0] = v.x;
            tile[c][f * 4 + 1] = v.y;
            tile[c][f * 4 + 2] = v.z;
            tile[c][f * 4 + 3] = v.w;
        }
        __syncthreads();
        const int ww = tid >> 1;
        const int c0 = (tid & 1) * 32;
        __bf16* dst = xn + (((size_t)(b * H_ + h)) * W_ + ww) * CIN_ + c0;
#pragma unroll
        for (int j = 0; j < 4; ++j) {
            bf16x8 o;
#pragma unroll
            for (int e = 0; e < 8; ++e) o[e] = (__bf16)tile[c0 + j * 8 + e][ww];
            *(bf16x8*)(dst + j * 8) = o;
        }
    } else {
        int idx = (blockIdx.x - 512) * 256 + tid;   // 9*2*4*64*8 = 36864
        if (idx >= K2_ * 2 * 4 * 64 * 8) return;
        int e    = idx & 7;
        int lane = (idx >> 3) & 63;
        int ct   = (idx >> 9) & 3;
        int s    = (idx >> 11) & 1;
        int k    = idx >> 12;
        int co   = ct * 16 + (lane & 15);
        int cin  = s * 32 + (lane >> 4) * 8 + e;
        wt3[idx] = (__bf16)w[(co * CIN_ + cin) * K2_ + k];
    }
}

// K-split DCNv2: 8 waves/block; waves {t, t+4} share one 16-px tile.
// Wave s in {0,1} gathers + MFMAs only cin half s*32..s*32+31 (partial sums),
// combined via LDS at the end. Doubles waves/SIMD at constant memory traffic.
__global__ __launch_bounds__(512, 8) void dcn_ksplit_kernel(
    const __bf16* __restrict__ xn,     // [B, H, W, Cin] bf16
    const float* __restrict__ offset,  // [B, 18, H, W]
    const float* __restrict__ mask,    // [B, 9, H, W]
    const __bf16* __restrict__ wt3,    // lane-linear A-frags [k][s][ct][lane][8]
    const float* __restrict__ bias,
    float* __restrict__ out)           // [B, Cout, H, W]
{
    __shared__ f32x4 s_red[4][4][64];  // 16 KB: [tile][ct][lane]

    const int tid  = threadIdx.x;
    const int wave = tid >> 6;
    const int lane = tid & 63;
    const int til  = wave & 3;    // tile within block
    const int ks   = wave >> 2;   // K half: 0 or 1
    const int n16  = lane & 15;
    const int kb   = lane >> 4;

    const int bid0 = blockIdx.x;
    const int bidx = (bid0 & 7) * 128 + (bid0 >> 3);   // bijective XCD swizzle

    const int b   = bidx >> 8;
    const int rem = bidx & 255;
    const int ho  = rem >> 1;
    const int w0  = (rem & 1) * 64 + til * 16;
    const int wos = w0 + n16;
    const int pix = ho * W_ + wos;

    const __bf16* xnb = xn + (size_t)b * HW_ * CIN_;
    const float* offb = offset + (size_t)b * (2 * K2_) * HW_ + pix;
    const float* mb   = mask   + (size_t)b * K2_ * HW_ + pix;

    const int cin_s = ks * 32 + kb * 8;

    f32x4 acc[4];
#pragma unroll
    for (int t = 0; t < 4; ++t) acc[t] = (f32x4){0.f, 0.f, 0.f, 0.f};

    float oy = offb[0];
    float ox = offb[HW_];
    float mm = mb[0];

#pragma unroll 1
    for (int k = 0; k < K2_; ++k) {
        const int ky = k / 3, kx = k % 3;
        const float py  = (float)(ho - 1 + ky) + oy;
        const float pxf = (float)(wos - 1 + kx) + ox;
        const float fy = floorf(py), fx = floorf(pxf);
        const int   y0 = (int)fy,    x0 = (int)fx;
        const float ly = py - fy,    lx = pxf - fx;

        const float vy0 = (y0 >= 0 && y0 < H_)         ? 1.f : 0.f;
        const float vy1 = (y0 + 1 >= 0 && y0 + 1 < H_) ? 1.f : 0.f;
        const float vx0 = (x0 >= 0 && x0 < W_)         ? 1.f : 0.f;
        const float vx1 = (x0 + 1 >= 0 && x0 + 1 < W_) ? 1.f : 0.f;
        const float W00 = mm * (1.f - ly) * (1.f - lx) * vy0 * vx0;
        const float W01 = mm * (1.f - ly) * lx         * vy0 * vx1;
        const float W10 = mm * ly * (1.f - lx)         * vy1 * vx0;
        const float W11 = mm * ly * lx                 * vy1 * vx1;
        const int cy0 = min(max(y0, 0), H_ - 1);
        const int cy1 = min(max(y0 + 1, 0), H_ - 1);
        const int cx0 = min(max(x0, 0), W_ - 1);
        const int cx1 = min(max(x0 + 1, 0), W_ - 1);

        const int i00 = (cy0 * W_ + cx0) * CIN_ + cin_s;
        const int i01 = (cy0 * W_ + cx1) * CIN_ + cin_s;
        const int i10 = (cy1 * W_ + cx0) * CIN_ + cin_s;
        const int i11 = (cy1 * W_ + cx1) * CIN_ + cin_s;

        const bf16x8 g00 = *(const bf16x8*)(xnb + i00);
        const bf16x8 g01 = *(const bf16x8*)(xnb + i01);
        const bf16x8 g10 = *(const bf16x8*)(xnb + i10);
        const bf16x8 g11 = *(const bf16x8*)(xnb + i11);

        if (k + 1 < K2_) {   // prefetch next tap's offsets under blend+MFMA
            oy = offb[(2 * (k + 1)) * HW_];
            ox = offb[(2 * (k + 1) + 1) * HW_];
            mm = mb[(k + 1) * HW_];
        }

        bf16x8 bfv;
#pragma unroll
        for (int e = 0; e < 8; ++e) {
            const float v = W00 * (float)g00[e] + W01 * (float)g01[e]
                          + W10 * (float)g10[e] + W11 * (float)g11[e];
            bfv[e] = (__bf16)v;
        }

        const __bf16* wk = wt3 + (size_t)k * (2 * 4 * 64 * 8) + (ks * 4) * 512 + lane * 8;
#pragma unroll
        for (int ct = 0; ct < 4; ++ct) {
            const bf16x8 A = *(const bf16x8*)(wk + ct * 512);
            acc[ct] = __builtin_amdgcn_mfma_f32_16x16x32_bf16(A, bfv, acc[ct], 0, 0, 0);
        }
    }

    // ---- combine K halves via LDS ----
    if (ks == 1) {
#pragma unroll
        for (int ct = 0; ct < 4; ++ct) s_red[til][ct][lane] = acc[ct];
    }
    __syncthreads();
    if (ks == 0) {
#pragma unroll
        for (int ct = 0; ct < 4; ++ct) {
            const f32x4 o = acc[ct] + s_red[til][ct][lane];
#pragma unroll
            for (int r = 0; r < 4; ++r) {
                const int co = ct * 16 + kb * 4 + r;
                out[((size_t)(b * COUT_ + co)) * HW_ + pix] = o[r] + bias[co];
            }
        }
    }
}

extern "C" void kernel_launch(void* const* d_in, const int* in_sizes, int n_in,
                              void* d_out, int out_size, void* d_ws, size_t ws_size,
                              hipStream_t stream) {
    const float* x      = (const float*)d_in[0];
    const float* offset = (const float*)d_in[1];
    const float* mask   = (const float*)d_in[2];
    const float* weight = (const float*)d_in[3];
    const float* bias   = (const float*)d_in[4];
    float* out = (float*)d_out;

    const size_t wt_bytes = (size_t)K2_ * 2 * 4 * 64 * 8 * 2;      // 73728
    __bf16* wt3 = (__bf16*)d_ws;
    __bf16* xn  = (__bf16*)((char*)d_ws + wt_bytes);               // 8 MB

    // prep: 512 repack blocks + 144 weight blocks
    prep_kernel<<<512 + (K2_ * 2 * 4 * 64 * 8 + 255) / 256, 256, 0, stream>>>(x, weight, xn, wt3);
    // main: 1024 blocks x 512 threads (8 waves: 4 tiles x 2 K-halves)
    dcn_ksplit_kernel<<<B_ * H_ * 2, 512, 0, stream>>>(xn, offset, mask, wt3, bias, out);
}

// Round 7
// 40.651 us; speedup vs baseline: 28.1984x; 1.4722x over previous
//
#include <hip/hip_runtime.h>
#include <math.h>

// DCNv2 forward: B=4, Cin=Cout=64, H=W=128, 3x3, stride=1, pad=1, dil=1, groups=dg=1
#define H_    128
#define W_    128
#define HW_   (H_ * W_)
#define CIN_  64
#define COUT_ 64
#define K2_   9
#define B_    4
#define NROWS 9
#define LDS_BYTES (NROWS * 128 * 128)   // 9 rows x 128 px x 8 chunks x 16B = 147456

typedef __bf16 bf16x8 __attribute__((ext_vector_type(8)));
typedef __bf16 bf16x4 __attribute__((ext_vector_type(4)));
typedef float  f32x4  __attribute__((ext_vector_type(4)));

// weight [Cout][Cin][3][3] -> lane-linear MFMA A-frag layout:
// wt3[k][s][ct][lane][e] = weight[ct*16+(lane&15)][s*32+(lane>>4)*8+e][k]
__global__ __launch_bounds__(256) void wtrans3_kernel(const float* __restrict__ w,
                                                      __bf16* __restrict__ wt3) {
    int idx = blockIdx.x * 256 + threadIdx.x;     // 9*2*4*64*8 = 36864
    if (idx >= K2_ * 2 * 4 * 64 * 8) return;
    int e    = idx & 7;
    int lane = (idx >> 3) & 63;
    int ct   = (idx >> 9) & 3;
    int s    = (idx >> 11) & 1;
    int k    = idx >> 12;
    int co   = ct * 16 + (lane & 15);
    int cin  = s * 32 + (lane >> 4) * 8 + e;
    wt3[idx] = (__bf16)w[(co * CIN_ + cin) * K2_ + k];
}

// One block = one output row (128 px), 512 thr = 8 waves x 16-px tiles.
// LDS holds rows [ho-4, ho+4] of x as bf16, chunk-swizzled:
//   record(slot, px) = 8 chunks x 16B (chunk j = cin j*8..j*8+7)
//   chunk j stored at slot q = (j + px + (px>>2)) & 7   (bank-conflict swizzle)
// Rare samples outside the 9-row window fall back to exec-masked global reads.
__global__ __launch_bounds__(512) void dcn_lds_kernel(
    const float* __restrict__ x,       // [B, Cin, H, W] fp32
    const float* __restrict__ offset,  // [B, 18, H, W]
    const float* __restrict__ mask,    // [B, 9, H, W]
    const __bf16* __restrict__ wt3,    // lane-linear A-frags
    const float* __restrict__ bias,
    float* __restrict__ out)           // [B, Cout, H, W]
{
    extern __shared__ char sm[];

    const int tid  = threadIdx.x;
    const int wave = tid >> 6;
    const int lane = tid & 63;
    const int n16  = lane & 15;
    const int kb   = lane >> 4;

    const int bid0 = blockIdx.x;                    // 512 blocks
    const int bidx = (bid0 & 7) * 64 + (bid0 >> 3); // bijective XCD swizzle
    const int b  = bidx >> 7;
    const int ho = bidx & 127;

    const float* xb = x + (size_t)b * CIN_ * HW_;

    // ---------- stage rows [ho-4, ho+4] into swizzled bf16 LDS ----------
    {
        const int cgroup = tid >> 5;      // 16 channel groups of 4
        const int px4    = tid & 31;      // 4-px granule
        const int c0     = cgroup * 4;
        const int chunk  = c0 >> 3;
        const int eoff   = (c0 & 7) * 2;  // byte offset within chunk (0 or 8)
#pragma unroll 1
        for (int r = 0; r < NROWS; ++r) {
            const int srow = min(max(ho - 4 + r, 0), H_ - 1);
            const float* g = xb + ((size_t)c0 * H_ + srow) * W_ + px4 * 4;
            const float4 v0 = *(const float4*)(g);
            const float4 v1 = *(const float4*)(g + HW_);
            const float4 v2 = *(const float4*)(g + 2 * HW_);
            const float4 v3 = *(const float4*)(g + 3 * HW_);
            const float* f0 = (const float*)&v0;
            const float* f1 = (const float*)&v1;
            const float* f2 = (const float*)&v2;
            const float* f3 = (const float*)&v3;
#pragma unroll
            for (int e = 0; e < 4; ++e) {
                const int px = px4 * 4 + e;
                const int q  = (chunk + px + (px >> 2)) & 7;
                bf16x4 pk;
                pk[0] = (__bf16)f0[e];
                pk[1] = (__bf16)f1[e];
                pk[2] = (__bf16)f2[e];
                pk[3] = (__bf16)f3[e];
                *(bf16x4*)(sm + (((size_t)r * 128 + px) * 8 + q) * 16 + eoff) = pk;
            }
        }
    }
    __syncthreads();

    // ---------- fused sample + MFMA ----------
    const int wos = wave * 16 + n16;
    const int pix = ho * W_ + wos;
    const float* offb = offset + (size_t)b * (2 * K2_) * HW_ + pix;
    const float* mb   = mask   + (size_t)b * K2_ * HW_ + pix;

    f32x4 acc[4];
#pragma unroll
    for (int t = 0; t < 4; ++t) acc[t] = (f32x4){0.f, 0.f, 0.f, 0.f};

    float oy = offb[0];
    float ox = offb[HW_];
    float mm = mb[0];

#pragma unroll 1
    for (int k = 0; k < K2_; ++k) {
        const int ky = k / 3, kx = k % 3;
        const float py  = (float)(ho - 1 + ky) + oy;
        const float pxf = (float)(wos - 1 + kx) + ox;
        const float fy = floorf(py), fx = floorf(pxf);
        const int   y0 = (int)fy,    x0 = (int)fx;
        const float ly = py - fy,    lx = pxf - fx;

        const float vy0 = (y0 >= 0 && y0 < H_)         ? 1.f : 0.f;
        const float vy1 = (y0 + 1 >= 0 && y0 + 1 < H_) ? 1.f : 0.f;
        const float vx0 = (x0 >= 0 && x0 < W_)         ? 1.f : 0.f;
        const float vx1 = (x0 + 1 >= 0 && x0 + 1 < W_) ? 1.f : 0.f;
        const float W00 = mm * (1.f - ly) * (1.f - lx) * vy0 * vx0;
        const float W01 = mm * (1.f - ly) * lx         * vy0 * vx1;
        const float W10 = mm * ly * (1.f - lx)         * vy1 * vx0;
        const float W11 = mm * ly * lx                 * vy1 * vx1;
        const int cy0 = min(max(y0, 0), H_ - 1);
        const int cy1 = min(max(y0 + 1, 0), H_ - 1);
        const int cx0 = min(max(x0, 0), W_ - 1);
        const int cx1 = min(max(x0 + 1, 0), W_ - 1);

        const int s0 = cy0 - ho + 4;
        const int s1 = cy1 - ho + 4;
        const bool need0 = ((unsigned)s0 > 8u) && (vy0 != 0.f);
        const bool need1 = ((unsigned)s1 > 8u) && (vy1 != 0.f);
        const int s0c = min(max(s0, 0), 8);
        const int s1c = min(max(s1, 0), 8);
        const int key0 = cx0 + (cx0 >> 2);
        const int key1 = cx1 + (cx1 >> 2);

        const char* r00 = sm + ((size_t)(s0c * 128 + cx0) * 8) * 16;
        const char* r01 = sm + ((size_t)(s0c * 128 + cx1) * 8) * 16;
        const char* r10 = sm + ((size_t)(s1c * 128 + cx0) * 8) * 16;
        const char* r11 = sm + ((size_t)(s1c * 128 + cx1) * 8) * 16;

        bf16x8 a00 = *(const bf16x8*)(r00 + (((kb     + key0) & 7) << 4));
        bf16x8 c00 = *(const bf16x8*)(r00 + (((kb + 4 + key0) & 7) << 4));
        bf16x8 a01 = *(const bf16x8*)(r01 + (((kb     + key1) & 7) << 4));
        bf16x8 c01 = *(const bf16x8*)(r01 + (((kb + 4 + key1) & 7) << 4));
        bf16x8 a10 = *(const bf16x8*)(r10 + (((kb     + key0) & 7) << 4));
        bf16x8 c10 = *(const bf16x8*)(r10 + (((kb + 4 + key0) & 7) << 4));
        bf16x8 a11 = *(const bf16x8*)(r11 + (((kb     + key1) & 7) << 4));
        bf16x8 c11 = *(const bf16x8*)(r11 + (((kb + 4 + key1) & 7) << 4));

        // rare out-of-window fallback (exec-masked; P ~ 0.3% per corner-row)
        if (__builtin_expect(need0, 0)) {
            const float* gl = xb + (size_t)(kb * 8) * HW_ + (size_t)cy0 * W_;
            const float* gh = gl + (size_t)32 * HW_;
#pragma unroll
            for (int e = 0; e < 8; ++e) {
                a00[e] = (__bf16)gl[(size_t)e * HW_ + cx0];
                a01[e] = (__bf16)gl[(size_t)e * HW_ + cx1];
                c00[e] = (__bf16)gh[(size_t)e * HW_ + cx0];
                c01[e] = (__bf16)gh[(size_t)e * HW_ + cx1];
            }
        }
        if (__builtin_expect(need1, 0)) {
            const float* gl = xb + (size_t)(kb * 8) * HW_ + (size_t)cy1 * W_;
            const float* gh = gl + (size_t)32 * HW_;
#pragma unroll
            for (int e = 0; e < 8; ++e) {
                a10[e] = (__bf16)gl[(size_t)e * HW_ + cx0];
                a11[e] = (__bf16)gl[(size_t)e * HW_ + cx1];
                c10[e] = (__bf16)gh[(size_t)e * HW_ + cx0];
                c11[e] = (__bf16)gh[(size_t)e * HW_ + cx1];
            }
        }

        if (k + 1 < K2_) {   // prefetch next tap's offsets
            oy = offb[(2 * (k + 1)) * HW_];
            ox = offb[(2 * (k + 1) + 1) * HW_];
            mm = mb[(k + 1) * HW_];
        }

        bf16x8 bf0, bf1;
#pragma unroll
        for (int e = 0; e < 8; ++e) {
            const float v0 = W00 * (float)a00[e] + W01 * (float)a01[e]
                           + W10 * (float)a10[e] + W11 * (float)a11[e];
            const float v1 = W00 * (float)c00[e] + W01 * (float)c01[e]
                           + W10 * (float)c10[e] + W11 * (float)c11[e];
            bf0[e] = (__bf16)v0;
            bf1[e] = (__bf16)v1;
        }

        const __bf16* wk = wt3 + (size_t)k * (2 * 4 * 64 * 8);
#pragma unroll
        for (int ct = 0; ct < 4; ++ct) {
            const bf16x8 A0 = *(const bf16x8*)(wk + (0 * 4 + ct) * 512 + lane * 8);
            const bf16x8 A1 = *(const bf16x8*)(wk + (1 * 4 + ct) * 512 + lane * 8);
            acc[ct] = __builtin_amdgcn_mfma_f32_16x16x32_bf16(A0, bf0, acc[ct], 0, 0, 0);
            acc[ct] = __builtin_amdgcn_mfma_f32_16x16x32_bf16(A1, bf1, acc[ct], 0, 0, 0);
        }
    }

    // ---------- epilogue: D col = n16 (px), row = kb*4 + r (+ ct*16) ----------
#pragma unroll
    for (int ct = 0; ct < 4; ++ct) {
#pragma unroll
        for (int r = 0; r < 4; ++r) {
            const int co = ct * 16 + kb * 4 + r;
            out[((size_t)(b * COUT_ + co)) * HW_ + pix] = acc[ct][r] + bias[co];
        }
    }
}

extern "C" void kernel_launch(void* const* d_in, const int* in_sizes, int n_in,
                              void* d_out, int out_size, void* d_ws, size_t ws_size,
                              hipStream_t stream) {
    const float* x      = (const float*)d_in[0];
    const float* offset = (const float*)d_in[1];
    const float* mask   = (const float*)d_in[2];
    const float* weight = (const float*)d_in[3];
    const float* bias   = (const float*)d_in[4];
    float* out = (float*)d_out;
    __bf16* wt3 = (__bf16*)d_ws;   // 73728 bytes

    // allow 147456 B dynamic LDS (gfx950 workgroup max is 160 KiB)
    hipFuncSetAttribute(reinterpret_cast<const void*>(dcn_lds_kernel),
                        hipFuncAttributeMaxDynamicSharedMemorySize, LDS_BYTES);

    wtrans3_kernel<<<(K2_ * 2 * 4 * 64 * 8 + 255) / 256, 256, 0, stream>>>(weight, wt3);
    dcn_lds_kernel<<<B_ * H_, 512, LDS_BYTES, stream>>>(x, offset, mask, wt3, bias, out);
}

// Round 8
// 38.897 us; speedup vs baseline: 29.4699x; 1.0451x over previous
//
#include <hip/hip_runtime.h>
#include <math.h>

// DCNv2 forward: B=4, Cin=Cout=64, H=W=128, 3x3, stride=1, pad=1, dil=1, groups=dg=1
#define H_    128
#define W_    128
#define HW_   (H_ * W_)
#define CIN_  64
#define COUT_ 64
#define K2_   9
#define B_    4
#define NROWS 9
#define LDS_BYTES (NROWS * 128 * 128)   // 9 rows x 128 px x 8 chunks x 16B = 147456

typedef __bf16 bf16x8 __attribute__((ext_vector_type(8)));
typedef __bf16 bf16x4 __attribute__((ext_vector_type(4)));
typedef float  f32x4  __attribute__((ext_vector_type(4)));

// weight [Cout][Cin][3][3] -> lane-linear MFMA A-frag layout:
// wt3[k][s][ct][lane][e] = weight[ct*16+(lane&15)][s*32+(lane>>4)*8+e][k]
__global__ __launch_bounds__(256) void wtrans3_kernel(const float* __restrict__ w,
                                                      __bf16* __restrict__ wt3) {
    int idx = blockIdx.x * 256 + threadIdx.x;     // 9*2*4*64*8 = 36864
    if (idx >= K2_ * 2 * 4 * 64 * 8) return;
    int e    = idx & 7;
    int lane = (idx >> 3) & 63;
    int ct   = (idx >> 9) & 3;
    int s    = (idx >> 11) & 1;
    int k    = idx >> 12;
    int co   = ct * 16 + (lane & 15);
    int cin  = s * 32 + (lane >> 4) * 8 + e;
    wt3[idx] = (__bf16)w[(co * CIN_ + cin) * K2_ + k];
}

// One block = one output row (128 px), 512 thr = 8 waves x 16-px tiles.
// LDS holds rows [ho-4, ho+4] of x as bf16, chunk-swizzled:
//   record(slot, px) = 8 chunks x 16B (chunk j = cin j*8..j*8+7)
//   chunk j stored at slot q = (j + px + (px>>3)) & 7
//   (px + (px>>3) spreads BOTH consecutive-px reads AND stride-4-px writes
//    across all 8 slots -> ~2-way everywhere, which is free)
// Rare samples outside the 9-row window fall back to exec-masked global reads.
__global__ __launch_bounds__(512, 2) void dcn_lds_kernel(
    const float* __restrict__ x,       // [B, Cin, H, W] fp32
    const float* __restrict__ offset,  // [B, 18, H, W]
    const float* __restrict__ mask,    // [B, 9, H, W]
    const __bf16* __restrict__ wt3,    // lane-linear A-frags
    const float* __restrict__ bias,
    float* __restrict__ out)           // [B, Cout, H, W]
{
    extern __shared__ char sm[];

    const int tid  = threadIdx.x;
    const int wave = tid >> 6;
    const int lane = tid & 63;
    const int n16  = lane & 15;
    const int kb   = lane >> 4;

    const int bid0 = blockIdx.x;                    // 512 blocks
    const int bidx = (bid0 & 7) * 64 + (bid0 >> 3); // bijective XCD swizzle
    const int b  = bidx >> 7;
    const int ho = bidx & 127;

    const float* xb = x + (size_t)b * CIN_ * HW_;

    // ---------- stage rows [ho-4, ho+4] into swizzled bf16 LDS ----------
    {
        const int cgroup = tid >> 5;      // 16 channel groups of 4
        const int px4    = tid & 31;      // 4-px granule
        const int c0     = cgroup * 4;
        const int chunk  = c0 >> 3;
        const int eoff   = (c0 & 7) * 2;  // byte offset within chunk (0 or 8)
#pragma unroll
        for (int r = 0; r < NROWS; ++r) {
            const int srow = min(max(ho - 4 + r, 0), H_ - 1);
            const float* g = xb + ((size_t)c0 * H_ + srow) * W_ + px4 * 4;
            const float4 v0 = *(const float4*)(g);
            const float4 v1 = *(const float4*)(g + HW_);
            const float4 v2 = *(const float4*)(g + 2 * HW_);
            const float4 v3 = *(const float4*)(g + 3 * HW_);
            const float* f0 = (const float*)&v0;
            const float* f1 = (const float*)&v1;
            const float* f2 = (const float*)&v2;
            const float* f3 = (const float*)&v3;
#pragma unroll
            for (int e = 0; e < 4; ++e) {
                const int px = px4 * 4 + e;
                const int q  = (chunk + px + (px >> 3)) & 7;
                bf16x4 pk;
                pk[0] = (__bf16)f0[e];
                pk[1] = (__bf16)f1[e];
                pk[2] = (__bf16)f2[e];
                pk[3] = (__bf16)f3[e];
                *(bf16x4*)(sm + (((size_t)r * 128 + px) * 8 + q) * 16 + eoff) = pk;
            }
        }
    }
    __syncthreads();

    // ---------- fused sample + MFMA ----------
    const int wos = wave * 16 + n16;
    const int pix = ho * W_ + wos;
    const float* offb = offset + (size_t)b * (2 * K2_) * HW_ + pix;
    const float* mb   = mask   + (size_t)b * K2_ * HW_ + pix;

    f32x4 acc[4];
#pragma unroll
    for (int t = 0; t < 4; ++t) acc[t] = (f32x4){0.f, 0.f, 0.f, 0.f};

    float oy = offb[0];
    float ox = offb[HW_];
    float mm = mb[0];

#pragma unroll 3
    for (int k = 0; k < K2_; ++k) {
        const int ky = k / 3, kx = k % 3;
        const float py  = (float)(ho - 1 + ky) + oy;
        const float pxf = (float)(wos - 1 + kx) + ox;
        const float fy = floorf(py), fx = floorf(pxf);
        const int   y0 = (int)fy,    x0 = (int)fx;
        const float ly = py - fy,    lx = pxf - fx;

        const float vy0 = (y0 >= 0 && y0 < H_)         ? 1.f : 0.f;
        const float vy1 = (y0 + 1 >= 0 && y0 + 1 < H_) ? 1.f : 0.f;
        const float vx0 = (x0 >= 0 && x0 < W_)         ? 1.f : 0.f;
        const float vx1 = (x0 + 1 >= 0 && x0 + 1 < W_) ? 1.f : 0.f;
        const float W00 = mm * (1.f - ly) * (1.f - lx) * vy0 * vx0;
        const float W01 = mm * (1.f - ly) * lx         * vy0 * vx1;
        const float W10 = mm * ly * (1.f - lx)         * vy1 * vx0;
        const float W11 = mm * ly * lx                 * vy1 * vx1;
        const int cy0 = min(max(y0, 0), H_ - 1);
        const int cy1 = min(max(y0 + 1, 0), H_ - 1);
        const int cx0 = min(max(x0, 0), W_ - 1);
        const int cx1 = min(max(x0 + 1, 0), W_ - 1);

        const int s0 = cy0 - ho + 4;
        const int s1 = cy1 - ho + 4;
        const bool need0 = ((unsigned)s0 > 8u) && (vy0 != 0.f);
        const bool need1 = ((unsigned)s1 > 8u) && (vy1 != 0.f);
        const int s0c = min(max(s0, 0), 8);
        const int s1c = min(max(s1, 0), 8);
        const int key0 = cx0 + (cx0 >> 3);
        const int key1 = cx1 + (cx1 >> 3);

        const char* r00 = sm + ((size_t)(s0c * 128 + cx0) * 8) * 16;
        const char* r01 = sm + ((size_t)(s0c * 128 + cx1) * 8) * 16;
        const char* r10 = sm + ((size_t)(s1c * 128 + cx0) * 8) * 16;
        const char* r11 = sm + ((size_t)(s1c * 128 + cx1) * 8) * 16;

        bf16x8 a00 = *(const bf16x8*)(r00 + (((kb     + key0) & 7) << 4));
        bf16x8 c00 = *(const bf16x8*)(r00 + (((kb + 4 + key0) & 7) << 4));
        bf16x8 a01 = *(const bf16x8*)(r01 + (((kb     + key1) & 7) << 4));
        bf16x8 c01 = *(const bf16x8*)(r01 + (((kb + 4 + key1) & 7) << 4));
        bf16x8 a10 = *(const bf16x8*)(r10 + (((kb     + key0) & 7) << 4));
        bf16x8 c10 = *(const bf16x8*)(r10 + (((kb + 4 + key0) & 7) << 4));
        bf16x8 a11 = *(const bf16x8*)(r11 + (((kb     + key1) & 7) << 4));
        bf16x8 c11 = *(const bf16x8*)(r11 + (((kb + 4 + key1) & 7) << 4));

        // rare out-of-window fallback (exec-masked; P ~ 0.3% per corner-row)
        if (__builtin_expect(need0, 0)) {
            const float* gl = xb + (size_t)(kb * 8) * HW_ + (size_t)cy0 * W_;
            const float* gh = gl + (size_t)32 * HW_;
#pragma unroll
            for (int e = 0; e < 8; ++e) {
                a00[e] = (__bf16)gl[(size_t)e * HW_ + cx0];
                a01[e] = (__bf16)gl[(size_t)e * HW_ + cx1];
                c00[e] = (__bf16)gh[(size_t)e * HW_ + cx0];
                c01[e] = (__bf16)gh[(size_t)e * HW_ + cx1];
            }
        }
        if (__builtin_expect(need1, 0)) {
            const float* gl = xb + (size_t)(kb * 8) * HW_ + (size_t)cy1 * W_;
            const float* gh = gl + (size_t)32 * HW_;
#pragma unroll
            for (int e = 0; e < 8; ++e) {
                a10[e] = (__bf16)gl[(size_t)e * HW_ + cx0];
                a11[e] = (__bf16)gl[(size_t)e * HW_ + cx1];
                c10[e] = (__bf16)gh[(size_t)e * HW_ + cx0];
                c11[e] = (__bf16)gh[(size_t)e * HW_ + cx1];
            }
        }

        if (k + 1 < K2_) {   // prefetch next tap's offsets
            oy = offb[(2 * (k + 1)) * HW_];
            ox = offb[(2 * (k + 1) + 1) * HW_];
            mm = mb[(k + 1) * HW_];
        }

        bf16x8 bf0, bf1;
#pragma unroll
        for (int e = 0; e < 8; ++e) {
            const float v0 = W00 * (float)a00[e] + W01 * (float)a01[e]
                           + W10 * (float)a10[e] + W11 * (float)a11[e];
            const float v1 = W00 * (float)c00[e] + W01 * (float)c01[e]
                           + W10 * (float)c10[e] + W11 * (float)c11[e];
            bf0[e] = (__bf16)v0;
            bf1[e] = (__bf16)v1;
        }

        const __bf16* wk = wt3 + (size_t)k * (2 * 4 * 64 * 8);
#pragma unroll
        for (int ct = 0; ct < 4; ++ct) {
            const bf16x8 A0 = *(const bf16x8*)(wk + (0 * 4 + ct) * 512 + lane * 8);
            const bf16x8 A1 = *(const bf16x8*)(wk + (1 * 4 + ct) * 512 + lane * 8);
            acc[ct] = __builtin_amdgcn_mfma_f32_16x16x32_bf16(A0, bf0, acc[ct], 0, 0, 0);
            acc[ct] = __builtin_amdgcn_mfma_f32_16x16x32_bf16(A1, bf1, acc[ct], 0, 0, 0);
        }
    }

    // ---------- epilogue: D col = n16 (px), row = kb*4 + r (+ ct*16) ----------
#pragma unroll
    for (int ct = 0; ct < 4; ++ct) {
#pragma unroll
        for (int r = 0; r < 4; ++r) {
            const int co = ct * 16 + kb * 4 + r;
            out[((size_t)(b * COUT_ + co)) * HW_ + pix] = acc[ct][r] + bias[co];
        }
    }
}

extern "C" void kernel_launch(void* const* d_in, const int* in_sizes, int n_in,
                              void* d_out, int out_size, void* d_ws, size_t ws_size,
                              hipStream_t stream) {
    const float* x      = (const float*)d_in[0];
    const float* offset = (const float*)d_in[1];
    const float* mask   = (const float*)d_in[2];
    const float* weight = (const float*)d_in[3];
    const float* bias   = (const float*)d_in[4];
    float* out = (float*)d_out;
    __bf16* wt3 = (__bf16*)d_ws;   // 73728 bytes

    // allow 147456 B dynamic LDS (gfx950 workgroup max is 160 KiB)
    hipFuncSetAttribute(reinterpret_cast<const void*>(dcn_lds_kernel),
                        hipFuncAttributeMaxDynamicSharedMemorySize, LDS_BYTES);

    wtrans3_kernel<<<(K2_ * 2 * 4 * 64 * 8 + 255) / 256, 256, 0, stream>>>(weight, wt3);
    dcn_lds_kernel<<<B_ * H_, 512, LDS_BYTES, stream>>>(x, offset, mask, wt3, bias, out);
}

// Round 9
// 33.089 us; speedup vs baseline: 34.6423x; 1.1755x over previous
//
#include <hip/hip_runtime.h>
#include <math.h>

// DCNv2 forward: B=4, Cin=Cout=64, H=W=128, 3x3, stride=1, pad=1, dil=1, groups=dg=1
#define H_    128
#define W_    128
#define HW_   (H_ * W_)
#define CIN_  64
#define COUT_ 64
#define K2_   9
#define B_    4
#define NROWS 10
#define LDS_BYTES (NROWS * 128 * 128)   // 10 rows x 128 px x 8 chunks x 16B = 163840 (160 KiB)

typedef __bf16 bf16x8 __attribute__((ext_vector_type(8)));
typedef __bf16 bf16x4 __attribute__((ext_vector_type(4)));
typedef float  f32x4  __attribute__((ext_vector_type(4)));

// weight [Cout][Cin][3][3] -> lane-linear MFMA A-frag layout:
// wt3[k][s][ct][lane][e] = weight[ct*16+(lane&15)][s*32+(lane>>4)*8+e][k]
__global__ __launch_bounds__(256) void wtrans3_kernel(const float* __restrict__ w,
                                                      __bf16* __restrict__ wt3) {
    int idx = blockIdx.x * 256 + threadIdx.x;     // 9*2*4*64*8 = 36864
    if (idx >= K2_ * 2 * 4 * 64 * 8) return;
    int e    = idx & 7;
    int lane = (idx >> 3) & 63;
    int ct   = (idx >> 9) & 3;
    int s    = (idx >> 11) & 1;
    int k    = idx >> 12;
    int co   = ct * 16 + (lane & 15);
    int cin  = s * 32 + (lane >> 4) * 8 + e;
    wt3[idx] = (__bf16)w[(co * CIN_ + cin) * K2_ + k];
}

// One block = 2 output rows (256 px), 1024 thr = 16 waves x 16-px tiles
// (wave>>3 selects the row, wave&7 the 16-px tile).
// LDS holds rows [ho0-4, ho0+5] of x as bf16, chunk-swizzled:
//   record(slot, px) = 8 chunks x 16B (chunk j = cin j*8..j*8+7)
//   chunk j stored at slot q = (j + px + (px>>3)) & 7
// Rare samples outside the 10-row window fall back to exec-masked global reads.
__global__ __launch_bounds__(1024, 4) void dcn_lds_kernel(
    const float* __restrict__ x,       // [B, Cin, H, W] fp32
    const float* __restrict__ offset,  // [B, 18, H, W]
    const float* __restrict__ mask,    // [B, 9, H, W]
    const __bf16* __restrict__ wt3,    // lane-linear A-frags
    const float* __restrict__ bias,
    float* __restrict__ out)           // [B, Cout, H, W]
{
    extern __shared__ char sm[];

    const int tid  = threadIdx.x;
    const int wave = tid >> 6;
    const int lane = tid & 63;
    const int n16  = lane & 15;
    const int kb   = lane >> 4;

    const int bid0 = blockIdx.x;                    // 256 blocks
    const int bidx = (bid0 & 7) * 32 + (bid0 >> 3); // bijective XCD swizzle
    const int b   = bidx >> 6;
    const int ho0 = (bidx & 63) * 2;                // base output row (even)

    const float* xb = x + (size_t)b * CIN_ * HW_;

    // ---------- stage rows [ho0-4, ho0+5] into swizzled bf16 LDS ----------
    {
        const int g5     = tid >> 5;      // 0..31
        const int px4    = tid & 31;      // 4-px granule
        const int rowpar = g5 >> 4;       // row parity 0/1
        const int c0     = (g5 & 15) * 4; // channel group of 4
        const int chunk  = c0 >> 3;
        const int eoff   = (c0 & 7) * 2;  // byte offset within chunk (0 or 8)
#pragma unroll
        for (int it = 0; it < 5; ++it) {
            const int r = it * 2 + rowpar;            // 0..9
            const int srow = min(max(ho0 - 4 + r, 0), H_ - 1);
            const float* g = xb + ((size_t)c0 * H_ + srow) * W_ + px4 * 4;
            const float4 v0 = *(const float4*)(g);
            const float4 v1 = *(const float4*)(g + HW_);
            const float4 v2 = *(const float4*)(g + 2 * HW_);
            const float4 v3 = *(const float4*)(g + 3 * HW_);
            const float* f0 = (const float*)&v0;
            const float* f1 = (const float*)&v1;
            const float* f2 = (const float*)&v2;
            const float* f3 = (const float*)&v3;
#pragma unroll
            for (int e = 0; e < 4; ++e) {
                const int px = px4 * 4 + e;
                const int q  = (chunk + px + (px >> 3)) & 7;
                bf16x4 pk;
                pk[0] = (__bf16)f0[e];
                pk[1] = (__bf16)f1[e];
                pk[2] = (__bf16)f2[e];
                pk[3] = (__bf16)f3[e];
                *(bf16x4*)(sm + (((size_t)r * 128 + px) * 8 + q) * 16 + eoff) = pk;
            }
        }
    }
    __syncthreads();

    // ---------- fused sample + MFMA ----------
    const int rr  = wave >> 3;            // which of the 2 output rows
    const int til = wave & 7;             // 16-px tile within the row
    const int ho  = ho0 + rr;
    const int wos = til * 16 + n16;
    const int pix = ho * W_ + wos;
    const float* offb = offset + (size_t)b * (2 * K2_) * HW_ + pix;
    const float* mb   = mask   + (size_t)b * K2_ * HW_ + pix;

    f32x4 acc[4];
#pragma unroll
    for (int t = 0; t < 4; ++t) acc[t] = (f32x4){0.f, 0.f, 0.f, 0.f};

    float oy = offb[0];
    float ox = offb[HW_];
    float mm = mb[0];

#pragma unroll 3
    for (int k = 0; k < K2_; ++k) {
        const int ky = k / 3, kx = k % 3;
        const float py  = (float)(ho - 1 + ky) + oy;
        const float pxf = (float)(wos - 1 + kx) + ox;
        const float fy = floorf(py), fx = floorf(pxf);
        const int   y0 = (int)fy,    x0 = (int)fx;
        const float ly = py - fy,    lx = pxf - fx;

        const float vy0 = (y0 >= 0 && y0 < H_)         ? 1.f : 0.f;
        const float vy1 = (y0 + 1 >= 0 && y0 + 1 < H_) ? 1.f : 0.f;
        const float vx0 = (x0 >= 0 && x0 < W_)         ? 1.f : 0.f;
        const float vx1 = (x0 + 1 >= 0 && x0 + 1 < W_) ? 1.f : 0.f;
        const float W00 = mm * (1.f - ly) * (1.f - lx) * vy0 * vx0;
        const float W01 = mm * (1.f - ly) * lx         * vy0 * vx1;
        const float W10 = mm * ly * (1.f - lx)         * vy1 * vx0;
        const float W11 = mm * ly * lx                 * vy1 * vx1;
        const int cy0 = min(max(y0, 0), H_ - 1);
        const int cy1 = min(max(y0 + 1, 0), H_ - 1);
        const int cx0 = min(max(x0, 0), W_ - 1);
        const int cx1 = min(max(x0 + 1, 0), W_ - 1);

        const int s0 = cy0 - ho0 + 4;               // window slot 0..9
        const int s1 = cy1 - ho0 + 4;
        const bool need0 = ((unsigned)s0 > 9u) && (vy0 != 0.f);
        const bool need1 = ((unsigned)s1 > 9u) && (vy1 != 0.f);
        const int s0c = min(max(s0, 0), 9);
        const int s1c = min(max(s1, 0), 9);
        const int key0 = cx0 + (cx0 >> 3);
        const int key1 = cx1 + (cx1 >> 3);

        const char* r00 = sm + ((size_t)(s0c * 128 + cx0) * 8) * 16;
        const char* r01 = sm + ((size_t)(s0c * 128 + cx1) * 8) * 16;
        const char* r10 = sm + ((size_t)(s1c * 128 + cx0) * 8) * 16;
        const char* r11 = sm + ((size_t)(s1c * 128 + cx1) * 8) * 16;

        bf16x8 a00 = *(const bf16x8*)(r00 + (((kb     + key0) & 7) << 4));
        bf16x8 c00 = *(const bf16x8*)(r00 + (((kb + 4 + key0) & 7) << 4));
        bf16x8 a01 = *(const bf16x8*)(r01 + (((kb     + key1) & 7) << 4));
        bf16x8 c01 = *(const bf16x8*)(r01 + (((kb + 4 + key1) & 7) << 4));
        bf16x8 a10 = *(const bf16x8*)(r10 + (((kb     + key0) & 7) << 4));
        bf16x8 c10 = *(const bf16x8*)(r10 + (((kb + 4 + key0) & 7) << 4));
        bf16x8 a11 = *(const bf16x8*)(r11 + (((kb     + key1) & 7) << 4));
        bf16x8 c11 = *(const bf16x8*)(r11 + (((kb + 4 + key1) & 7) << 4));

        // rare out-of-window fallback (exec-masked)
        if (__builtin_expect(need0, 0)) {
            const float* gl = xb + (size_t)(kb * 8) * HW_ + (size_t)cy0 * W_;
            const float* gh = gl + (size_t)32 * HW_;
#pragma unroll
            for (int e = 0; e < 8; ++e) {
                a00[e] = (__bf16)gl[(size_t)e * HW_ + cx0];
                a01[e] = (__bf16)gl[(size_t)e * HW_ + cx1];
                c00[e] = (__bf16)gh[(size_t)e * HW_ + cx0];
                c01[e] = (__bf16)gh[(size_t)e * HW_ + cx1];
            }
        }
        if (__builtin_expect(need1, 0)) {
            const float* gl = xb + (size_t)(kb * 8) * HW_ + (size_t)cy1 * W_;
            const float* gh = gl + (size_t)32 * HW_;
#pragma unroll
            for (int e = 0; e < 8; ++e) {
                a10[e] = (__bf16)gl[(size_t)e * HW_ + cx0];
                a11[e] = (__bf16)gl[(size_t)e * HW_ + cx1];
                c10[e] = (__bf16)gh[(size_t)e * HW_ + cx0];
                c11[e] = (__bf16)gh[(size_t)e * HW_ + cx1];
            }
        }

        if (k + 1 < K2_) {   // prefetch next tap's offsets
            oy = offb[(2 * (k + 1)) * HW_];
            ox = offb[(2 * (k + 1) + 1) * HW_];
            mm = mb[(k + 1) * HW_];
        }

        bf16x8 bf0, bf1;
#pragma unroll
        for (int e = 0; e < 8; ++e) {
            const float v0 = W00 * (float)a00[e] + W01 * (float)a01[e]
                           + W10 * (float)a10[e] + W11 * (float)a11[e];
            const float v1 = W00 * (float)c00[e] + W01 * (float)c01[e]
                           + W10 * (float)c10[e] + W11 * (float)c11[e];
            bf0[e] = (__bf16)v0;
            bf1[e] = (__bf16)v1;
        }

        const __bf16* wk = wt3 + (size_t)k * (2 * 4 * 64 * 8);
#pragma unroll
        for (int ct = 0; ct < 4; ++ct) {
            const bf16x8 A0 = *(const bf16x8*)(wk + (0 * 4 + ct) * 512 + lane * 8);
            const bf16x8 A1 = *(const bf16x8*)(wk + (1 * 4 + ct) * 512 + lane * 8);
            acc[ct] = __builtin_amdgcn_mfma_f32_16x16x32_bf16(A0, bf0, acc[ct], 0, 0, 0);
            acc[ct] = __builtin_amdgcn_mfma_f32_16x16x32_bf16(A1, bf1, acc[ct], 0, 0, 0);
        }
    }

    // ---------- epilogue: D col = n16 (px), row = kb*4 + r (+ ct*16) ----------
#pragma unroll
    for (int ct = 0; ct < 4; ++ct) {
#pragma unroll
        for (int r = 0; r < 4; ++r) {
            const int co = ct * 16 + kb * 4 + r;
            out[((size_t)(b * COUT_ + co)) * HW_ + pix] = acc[ct][r] + bias[co];
        }
    }
}

extern "C" void kernel_launch(void* const* d_in, const int* in_sizes, int n_in,
                              void* d_out, int out_size, void* d_ws, size_t ws_size,
                              hipStream_t stream) {
    const float* x      = (const float*)d_in[0];
    const float* offset = (const float*)d_in[1];
    const float* mask   = (const float*)d_in[2];
    const float* weight = (const float*)d_in[3];
    const float* bias   = (const float*)d_in[4];
    float* out = (float*)d_out;
    __bf16* wt3 = (__bf16*)d_ws;   // 73728 bytes

    // allow 163840 B dynamic LDS (gfx950 workgroup max is 160 KiB)
    hipFuncSetAttribute(reinterpret_cast<const void*>(dcn_lds_kernel),
                        hipFuncAttributeMaxDynamicSharedMemorySize, LDS_BYTES);

    wtrans3_kernel<<<(K2_ * 2 * 4 * 64 * 8 + 255) / 256, 256, 0, stream>>>(weight, wt3);
    // 256 blocks x 1024 threads: one block per CU, 2 output rows per block
    dcn_lds_kernel<<<B_ * H_ / 2, 1024, LDS_BYTES, stream>>>(x, offset, mask, wt3, bias, out);
}